// Round 9
// baseline (118.970 us; speedup 1.0000x reference)
//
#include <hip/hip_runtime.h>
#include <hip/hip_bf16.h>
#include <hip/hip_fp16.h>
#include <stdint.h>

typedef __attribute__((ext_vector_type(8))) _Float16 f16x8;
typedef __attribute__((ext_vector_type(4))) float f32x4;

#define B_  32
#define S_  512
#define K_  512
#define H_  1024
#define HS  32           // h-cols per block
#define SC  128          // s-rows per chunk
#define NKT 16           // K_/32
#define NSC 4            // S_/SC

// LDS: x dbuf 2x8K | W dbuf 2x6K = 28KB -> 4 blocks/CU (112KB) at
// __launch_bounds__(256,4). Handoff (2 sw x 32 h x {F,G} = 512B) aliases the
// WD1 tail (dead between kt15's barrier and next chunk kt0's stage).
// Swizzle (BK=32, 64B rows): logical slot j of row r stored at LDS slot
// j ^ (r&3) ^ ((r>>2)&3). Read (quarter-wave = fq): slot = fq ^ (fr&3) ^
// ((fr>>2)&3) -> <=2 lanes/bank (free). Stage side: lane l writes LDS slot
// l&3 of row r=cid*16+(l>>2); source slot = (l&3)^(r&3)^((r>>2)&3) is a pure
// lane function -> linear LDS dest, pre-swizzled global source (rule #21).
#define XD0 0
#define XD1 8192
#define WD0 16384
#define WD1 22528
#define HOF WD1
#define LDS_BYTES 28672

#define GLDS(src, dst) __builtin_amdgcn_global_load_lds( \
    (const __attribute__((address_space(1))) void*)(src), \
    (__attribute__((address_space(3))) void*)(dst), 16, 0, 0)

__device__ inline float sigm(float v) {
    return __builtin_amdgcn_rcpf(1.f + __expf(-v));
}

// ---------------------------------------------------------------------------
// f32 -> f16 conversion for x and W. 8 elems/thread, 16B stores.
// ---------------------------------------------------------------------------
struct alignas(16) H8 { _Float16 h[8]; };

__global__ __launch_bounds__(256) void cvt_xw(
    const float* __restrict__ x, _Float16* __restrict__ xh, int n8x,
    const float* __restrict__ W, _Float16* __restrict__ Wh, int n8w)
{
    const int t = blockIdx.x * 256 + threadIdx.x;
    const float* src; _Float16* dst; int i;
    if (t < n8x)             { src = x; dst = xh; i = t; }
    else if (t < n8x + n8w)  { src = W; dst = Wh; i = t - n8x; }
    else return;
    const float4* p = (const float4*)(src + (size_t)i * 8);
    const float4 a = p[0], b = p[1];
    H8 o;
    o.h[0] = (_Float16)a.x; o.h[1] = (_Float16)a.y;
    o.h[2] = (_Float16)a.z; o.h[3] = (_Float16)a.w;
    o.h[4] = (_Float16)b.x; o.h[5] = (_Float16)b.y;
    o.h[6] = (_Float16)b.z; o.h[7] = (_Float16)b.w;
    ((H8*)dst)[i] = o;
}

// ---------------------------------------------------------------------------
// Fused GEMM + activations + in-register affine scan + output.
// Grid 1024 = (b, hs), XCD-affine (b = (bid&7) + 8*((bid>>3)&3): each XCD
// sees 4 b's). Block 256 = 4 waves (2 sw x 2 hw); wave = 64 s x 3 gates x
// 16 h, acc[4][3], one h-column per lane (h = hw*16+fr, s-quarter = fq).
// K-loop: BK=32, 16 kt, 1 barrier/kt: stage(kt+1) -> 7 ds_read -> 12 MFMA.
// Scan: per-lane 4-step run composition, Kogge-Stone over fq (shfl),
// (F,G) handoff between sw waves via 512B LDS; backfill writes f32 out.
// ---------------------------------------------------------------------------
__global__ __launch_bounds__(256, 4) void qrnn_fused(
    const _Float16* __restrict__ xh,   // [B*S, K]
    const _Float16* __restrict__ Wh,   // [3H, K]
    const float* __restrict__ bias,    // [3H]
    const float* __restrict__ c0,      // [B, H]
    float* __restrict__ out)           // [B,S,H] ++ [B,H]
{
    extern __shared__ char smem[];

    const int tid  = threadIdx.x;
    const int lane = tid & 63;
    const int wid  = tid >> 6;
    const int hw   = wid & 1;          // h-half (16 h)
    const int sw   = wid >> 1;         // s-half (64 s)
    const int fq   = lane >> 4;
    const int fr   = lane & 15;

    const int bid = blockIdx.x;
    const int b   = (bid & 7) + 8 * ((bid >> 3) & 3);
    const int hs  = bid >> 5;

    const int hcol = hs * HS + hw * 16 + fr;
    const float bz  = bias[hcol];
    const float bff = bias[H_ + hcol];
    const float bo  = bias[2 * H_ + hcol];
    float cc = c0[b * H_ + hcol];

    // staging lane constants: row-sub = lane>>2, swizzled 16B slot
    const int lrow    = lane >> 2;
    const int lslot   = (lane & 3) ^ (lrow & 3) ^ (lane >> 4);
    const size_t loff = (size_t)lrow * (K_ * 2) + (lslot << 4);
    const char* xbase = (const char*)(xh + (size_t)(b * S_) * K_);
    const char* wbase = (const char*)Wh;

    auto STAGE = [&](int sc_, int kt_, int xoff, int woff) {
        #pragma unroll
        for (int i = 0; i < 4; ++i) {
            const int cid = wid + i * 4;          // 0..15, waves 2,3 skip 14,15
            if (cid >= 14) continue;
            if (cid < 8) {                        // x rows r = cid*16+lrow
                const char* src = xbase + (size_t)(sc_ * SC + cid * 16) * (K_ * 2)
                                + kt_ * 64 + loff;
                GLDS(src, smem + xoff + cid * 1024);
            } else {                              // W rows rW = (cid-8)*16+lrow
                const int w = cid - 8;            // gate = w>>1, hsub = (w&1)*16
                const int wrow0 = (w >> 1) * H_ + hs * HS + (w & 1) * 16;
                const char* src = wbase + (size_t)wrow0 * (K_ * 2) + kt_ * 64 + loff;
                GLDS(src, smem + woff + w * 1024);
            }
        }
    };

    // kt-invariant frag read offsets (swizzle is a pure lane function)
    const int rdsw = (fq ^ (fr & 3) ^ ((fr >> 2) & 3)) << 4;
    int afo[4], bfo[3];
    #pragma unroll
    for (int m = 0; m < 4; ++m) afo[m] = (sw * 64 + m * 16 + fr) * 64 + rdsw;
    #pragma unroll
    for (int n = 0; n < 3; ++n) bfo[n] = (n * 32 + hw * 16 + fr) * 64 + rdsw;

    STAGE(0, 0, XD0, WD0);
    __syncthreads();

    for (int sc = 0; sc < NSC; ++sc) {
        f32x4 acc[4][3] = {};

        #pragma unroll
        for (int kt = 0; kt < NKT; ++kt) {
            const int curx = (kt & 1) ? XD1 : XD0;
            const int curw = (kt & 1) ? WD1 : WD0;
            const int nxtx = (kt & 1) ? XD0 : XD1;
            const int nxtw = (kt & 1) ? WD0 : WD1;

            if (kt + 1 < NKT)      STAGE(sc, kt + 1, nxtx, nxtw);
            else if (sc + 1 < NSC) STAGE(sc + 1, 0, nxtx, nxtw);

            f16x8 af[4], bf[3];
            #pragma unroll
            for (int m = 0; m < 4; ++m)
                af[m] = *(const f16x8*)(smem + curx + afo[m]);
            #pragma unroll
            for (int n = 0; n < 3; ++n)
                bf[n] = *(const f16x8*)(smem + curw + bfo[n]);

            __builtin_amdgcn_s_setprio(1);
            #pragma unroll
            for (int m = 0; m < 4; ++m)
                #pragma unroll
                for (int n = 0; n < 3; ++n)
                    acc[m][n] = __builtin_amdgcn_mfma_f32_16x16x32_f16(
                        af[m], bf[n], acc[m][n], 0, 0, 0);
            __builtin_amdgcn_s_setprio(0);
            __syncthreads();   // stage landed; cur reads done before reuse
        }

        // ---- activations + per-lane affine composition ----------------------
        // step: c <- f*c + g, g = (1-f)*z. acc: [m][0]=g, [m][1]=f, [m][2]=o.
        float FsS[4], GsS[4];
        float FP = 1.f, GP = 0.f;
        #pragma unroll
        for (int m = 0; m < 4; ++m) {
            float Fr = 1.f, Gr = 0.f;
            #pragma unroll
            for (int j = 0; j < 4; ++j) {
                const float z = 2.f * sigm(2.f * (acc[m][0][j] + bz)) - 1.f;
                const float f = sigm(acc[m][1][j] + bff);
                const float g = (1.f - f) * z;
                acc[m][0][j] = g;
                acc[m][1][j] = f;
                acc[m][2][j] = sigm(acc[m][2][j] + bo);
                Gr = __builtin_fmaf(f, Gr, g);
                Fr = f * Fr;
            }
            // Kogge-Stone over fq (4 groups of 16 lanes)
            float F1 = __shfl(Fr, lane - 16), G1 = __shfl(Gr, lane - 16);
            if (fq >= 1) { Gr = __builtin_fmaf(Fr, G1, Gr); Fr = Fr * F1; }
            float F2 = __shfl(Fr, lane - 32), G2 = __shfl(Gr, lane - 32);
            if (fq >= 2) { Gr = __builtin_fmaf(Fr, G2, Gr); Fr = Fr * F2; }
            float FE = __shfl(Fr, lane - 16), GE = __shfl(Gr, lane - 16);
            if (fq == 0) { FE = 1.f; GE = 0.f; }
            const float FM = __shfl(Fr, 48 + fr);   // full 16-step map of m
            const float GM = __shfl(Gr, 48 + fr);
            FsS[m] = FE * FP;
            GsS[m] = __builtin_fmaf(FE, GP, GE);
            GP = __builtin_fmaf(FM, GP, GM);
            FP = FM * FP;
        }

        // ---- handoff: per-h wave-total (F,G) between sw waves ---------------
        const int hh = hw * 16 + fr;
        if (fq == 0)
            *(float2*)(smem + HOF + sw * 256 + hh * 8) = make_float2(FP, GP);
        asm volatile("s_waitcnt lgkmcnt(0)" ::: "memory");
        __builtin_amdgcn_s_barrier();

        // ---- backfill + out stores ------------------------------------------
        {
            const float2 m0 = *(const float2*)(smem + HOF + hh * 8);
            const float2 m1 = *(const float2*)(smem + HOF + 256 + hh * 8);
            const float cin = (sw == 0) ? cc : __builtin_fmaf(m0.x, cc, m0.y);
            #pragma unroll
            for (int m = 0; m < 4; ++m) {
                float cr = __builtin_fmaf(FsS[m], cin, GsS[m]);
                #pragma unroll
                for (int j = 0; j < 4; ++j) {
                    cr = __builtin_fmaf(acc[m][1][j], cr, acc[m][0][j]);
                    const int sg = b * S_ + sc * SC + sw * 64 + m * 16 + fq * 4 + j;
                    out[(size_t)sg * H_ + hcol] = acc[m][2][j] * cr;
                }
            }
            cc = __builtin_fmaf(m1.x, __builtin_fmaf(m0.x, cc, m0.y), m1.y);
        }
        asm volatile("s_waitcnt lgkmcnt(0)" ::: "memory");
        __builtin_amdgcn_s_barrier();   // handoff consumed before next stage
    }

    // c_last tail: [1,B,H] appended after [B,S,H]
    if (sw == 0 && fq == 0)
        out[(size_t)B_ * S_ * H_ + b * H_ + hcol] = cc;
}

extern "C" void kernel_launch(void* const* d_in, const int* in_sizes, int n_in,
                              void* d_out, int out_size, void* d_ws, size_t ws_size,
                              hipStream_t stream) {
    const float* x = (const float*)d_in[0];
    const float* h = (const float*)d_in[1];
    const float* W = (const float*)d_in[2];
    const float* b = (const float*)d_in[3];
    float* out = (float*)d_out;

    _Float16* xh = (_Float16*)d_ws;
    _Float16* Wh = xh + (size_t)B_ * S_ * K_;

    const int n8x = B_ * S_ * K_ / 8;   // 1048576
    const int n8w = 3 * H_ * K_ / 8;    // 196608
    cvt_xw<<<(n8x + n8w + 255) / 256, 256, 0, stream>>>(x, xh, n8x, W, Wh, n8w);

    qrnn_fused<<<B_ * (H_ / HS), 256, LDS_BYTES, stream>>>(xh, Wh, b, h, out);
}

// Round 10
// 84.195 us; speedup vs baseline: 1.4130x; 1.4130x over previous
//
#include <hip/hip_runtime.h>
#include <hip/hip_bf16.h>
#include <hip/hip_fp16.h>
#include <stdint.h>

typedef __attribute__((ext_vector_type(8))) _Float16 f16x8;
typedef __attribute__((ext_vector_type(4))) float f32x4;

#define B_  32
#define S_  512
#define K_  512
#define H_  1024
#define HS  64           // h-cols per block
#define SC  128          // s-rows per chunk
#define NKT 8            // K_/64
#define NSC 4            // S_/SC

// LDS: x dbuf 2x16K | W dbuf 2x24K = 80KB -> 2 blocks/CU.
// handoff (2 sw x 64 h x {F,G} f32 = 1KB) aliases the WD1 tail (rows 184..191
// of the W tile). WD1 is read up to the pre-HOF barrier of each chunk and
// next written by kt0's stage(kt1), which issues only after kt0's start
// barrier -- by then backfill consumed HOF (reads land before their stores).
#define XD0 0
#define XD1 16384
#define WD0 32768
#define WD1 57344
#define HOF (WD1 + 24576 - 1024)
#define LDS_BYTES 81920

#define GLDS(src, dst) __builtin_amdgcn_global_load_lds( \
    (const __attribute__((address_space(1))) void*)(src), \
    (__attribute__((address_space(3))) void*)(dst), 16, 0, 0)

__device__ inline float sigm(float v) {
    return __builtin_amdgcn_rcpf(1.f + __expf(-v));
}

// ---------------------------------------------------------------------------
// f32 -> f16 conversion for x and W. 8 elems/thread, 16B stores.
// ---------------------------------------------------------------------------
struct alignas(16) H8 { _Float16 h[8]; };

__global__ __launch_bounds__(256) void cvt_xw(
    const float* __restrict__ x, _Float16* __restrict__ xh, int n8x,
    const float* __restrict__ W, _Float16* __restrict__ Wh, int n8w)
{
    const int t = blockIdx.x * 256 + threadIdx.x;
    const float* src; _Float16* dst; int i;
    if (t < n8x)             { src = x; dst = xh; i = t; }
    else if (t < n8x + n8w)  { src = W; dst = Wh; i = t - n8x; }
    else return;
    const float4* p = (const float4*)(src + (size_t)i * 8);
    const float4 a = p[0], b = p[1];
    H8 o;
    o.h[0] = (_Float16)a.x; o.h[1] = (_Float16)a.y;
    o.h[2] = (_Float16)a.z; o.h[3] = (_Float16)a.w;
    o.h[4] = (_Float16)b.x; o.h[5] = (_Float16)b.y;
    o.h[6] = (_Float16)b.z; o.h[7] = (_Float16)b.w;
    ((H8*)dst)[i] = o;
}

// ---------------------------------------------------------------------------
// Fused GEMM + activations + in-register affine scan + output.
// Round-8 geometry (proven): grid 512 = (b, hs) XCD-affine; block 256 =
// 4 waves (sw x gw); wave = 64 s x {z,f,o} x 32 h; acc[4][6]; BK=64,
// 128B-row XOR swizzle (m97-proven).
// T4 schedule change: per kt = [vmcnt(counted) + s_barrier] -> 20 ds_read ->
// STAGE(kt+1) issue (stays in flight across the next barrier) -> 48 MFMA.
// No vmcnt(0) ever drains freshly-issued loads: at kt-start the only
// outstanding VMEM is the stage issued a full kt earlier (latency covered
// by the previous MFMA block). Chunk-start kt0 uses vmcnt(32): the 32
// backfill stores (newer, FIFO) may fly while the 10 older stage loads are
// guaranteed landed.
// ---------------------------------------------------------------------------
__global__ __launch_bounds__(256, 2) void qrnn_fused(
    const _Float16* __restrict__ xh,   // [B*S, K]
    const _Float16* __restrict__ Wh,   // [3H, K]
    const float* __restrict__ bias,    // [3H]
    const float* __restrict__ c0,      // [B, H]
    float* __restrict__ out)           // [B,S,H] ++ [B,H]
{
    extern __shared__ char smem[];

    const int tid  = threadIdx.x;
    const int lane = tid & 63;
    const int wid  = tid >> 6;
    const int gw   = wid & 1;          // h-half (32 h)
    const int sw   = wid >> 1;         // s-half (64 s)
    const int fq   = lane >> 4;
    const int fr   = lane & 15;

    const int bid = blockIdx.x;
    const int b   = (bid & 7) + ((bid >> 7) << 3);
    const int hs  = (bid >> 3) & 15;

    // per-lane h columns (nn = 0,1) and bias
    float bz[2], bff[2], bo[2], cc[2];
    #pragma unroll
    for (int nn = 0; nn < 2; ++nn) {
        const int hcol = hs * HS + gw * 32 + nn * 16 + fr;
        bz[nn]  = bias[hcol];
        bff[nn] = bias[H_ + hcol];
        bo[nn]  = bias[2 * H_ + hcol];
        cc[nn]  = c0[b * H_ + hcol];
    }

    const int srow  = lane >> 3;
    const int scolb = (((lane & 7) ^ (lane >> 3)) << 4);
    const _Float16* xbase = xh + (size_t)(b * S_) * K_;

    auto STAGE = [&](int sc_, int kt_, int xoff, int woff) {
        #pragma unroll
        for (int i = 0; i < 10; ++i) {
            const int cid = wid * 10 + i;          // 0..39 chunks of 1KB
            if (cid < 16) {                        // x tile rows (s')
                const int r = cid * 8 + srow;
                const char* src = (const char*)(xbase + (size_t)(sc_ * SC + r) * K_ + kt_ * 64) + scolb;
                GLDS(src, smem + xoff + cid * 1024);
            } else {                               // W tile rows (0..191)
                const int r = (cid - 16) * 8 + srow;
                const int wrow = (r >> 6) * H_ + hs * HS + (r & 63);
                const char* src = (const char*)(Wh + (size_t)wrow * K_ + kt_ * 64) + scolb;
                GLDS(src, smem + woff + (cid - 16) * 1024);
            }
        }
    };

    STAGE(0, 0, XD0, WD0);
    asm volatile("s_waitcnt vmcnt(0)" ::: "memory");   // drain prologue stage

    for (int sc = 0; sc < NSC; ++sc) {
        f32x4 acc[4][6] = {};

        #pragma unroll
        for (int kt = 0; kt < NKT; ++kt) {
            const int cur  = kt & 1;
            const int curx = cur ? XD1 : XD0;
            const int curw = cur ? WD1 : WD0;
            const int nxtx = cur ? XD0 : XD1;
            const int nxtw = cur ? WD0 : WD1;

            // --- start-of-kt sync: cur buffer landed on all waves ---------
            if (kt == 0) {
                // outstanding: 10 stage loads (oldest) + <=32 backfill stores
                asm volatile("s_waitcnt vmcnt(32)" ::: "memory");
            } else {
                asm volatile("s_waitcnt vmcnt(0)" ::: "memory");
            }
            __builtin_amdgcn_s_barrier();
            __builtin_amdgcn_sched_barrier(0);

            f16x8 af[2][4], bf[2][6];
            #pragma unroll
            for (int ks = 0; ks < 2; ++ks) {
                #pragma unroll
                for (int m = 0; m < 4; ++m) {
                    const int row = sw * 64 + m * 16 + fr;
                    const int kb  = ks * 64 + fq * 16;
                    af[ks][m] = *(const f16x8*)(smem + curx + row * 128 + (kb ^ ((row & 7) << 4)));
                }
                #pragma unroll
                for (int n = 0; n < 6; ++n) {
                    const int row = (n >> 1) * 64 + gw * 32 + (n & 1) * 16 + fr;
                    const int kb  = ks * 64 + fq * 16;
                    bf[ks][n] = *(const f16x8*)(smem + curw + row * 128 + (kb ^ ((row & 7) << 4)));
                }
            }

            // prefetch issue AFTER the wait point: flies across next barrier
            if (kt + 1 < NKT)      STAGE(sc, kt + 1, nxtx, nxtw);
            else if (sc + 1 < NSC) STAGE(sc + 1, 0, nxtx, nxtw);

            __builtin_amdgcn_s_setprio(1);
            #pragma unroll
            for (int ks = 0; ks < 2; ++ks)
                #pragma unroll
                for (int m = 0; m < 4; ++m)
                    #pragma unroll
                    for (int n = 0; n < 6; ++n)
                        acc[m][n] = __builtin_amdgcn_mfma_f32_16x16x32_f16(
                            af[ks][m], bf[ks][n], acc[m][n], 0, 0, 0);
            __builtin_amdgcn_s_setprio(0);
            // no end-of-kt barrier: next kt's start handles it
        }

        // ---- activations + per-lane affine composition ----------------------
        // step: c <- f*c + g, g = (1-f)*z. acc slots after this pass:
        // [m][nn] = g, [m][2+nn] = f, [m][4+nn] = o (all f32).
        float FsS[2][4], GsS[2][4];   // chunk-start -> run(m)-start coeffs
        float FP[2], GP[2];           // wave-total map (exclusive prefix over m)
        #pragma unroll
        for (int nn = 0; nn < 2; ++nn) {
            FP[nn] = 1.f; GP[nn] = 0.f;
            #pragma unroll
            for (int m = 0; m < 4; ++m) {
                float Fr = 1.f, Gr = 0.f;
                #pragma unroll
                for (int j = 0; j < 4; ++j) {
                    const float z = 2.f * sigm(2.f * (acc[m][nn][j] + bz[nn])) - 1.f;
                    const float f = sigm(acc[m][2 + nn][j] + bff[nn]);
                    const float g = (1.f - f) * z;
                    acc[m][nn][j]     = g;
                    acc[m][2 + nn][j] = f;
                    acc[m][4 + nn][j] = sigm(acc[m][4 + nn][j] + bo[nn]);
                    Gr = __builtin_fmaf(f, Gr, g);
                    Fr = f * Fr;
                }
                // Kogge-Stone over fq (4 groups of 16 lanes)
                float F1 = __shfl(Fr, lane - 16), G1 = __shfl(Gr, lane - 16);
                if (fq >= 1) { Gr = __builtin_fmaf(Fr, G1, Gr); Fr = Fr * F1; }
                float F2 = __shfl(Fr, lane - 32), G2 = __shfl(Gr, lane - 32);
                if (fq >= 2) { Gr = __builtin_fmaf(Fr, G2, Gr); Fr = Fr * F2; }
                float FE = __shfl(Fr, lane - 16), GE = __shfl(Gr, lane - 16);
                if (fq == 0) { FE = 1.f; GE = 0.f; }
                const float FM = __shfl(Fr, 48 + fr);   // full 16-step map of m
                const float GM = __shfl(Gr, 48 + fr);
                FsS[nn][m] = FE * FP[nn];
                GsS[nn][m] = __builtin_fmaf(FE, GP[nn], GE);
                GP[nn] = __builtin_fmaf(FM, GP[nn], GM);
                FP[nn] = FM * FP[nn];
            }
        }

        // all waves done reading WD1 (kt7 frags) before HOF write aliases it
        __builtin_amdgcn_s_barrier();

        // ---- handoff: per-h wave-total (F,G) between sw waves ---------------
        if (fq == 0) {
            #pragma unroll
            for (int nn = 0; nn < 2; ++nn) {
                const int hh = gw * 32 + nn * 16 + fr;
                *(float2*)(smem + HOF + sw * 512 + hh * 8) = make_float2(FP[nn], GP[nn]);
            }
        }
        asm volatile("s_waitcnt lgkmcnt(0)" ::: "memory");
        __builtin_amdgcn_s_barrier();

        // ---- backfill + out stores ------------------------------------------
        #pragma unroll
        for (int nn = 0; nn < 2; ++nn) {
            const int hh = gw * 32 + nn * 16 + fr;
            const float2 m0 = *(const float2*)(smem + HOF + hh * 8);
            const float2 m1 = *(const float2*)(smem + HOF + 512 + hh * 8);
            const float cin = (sw == 0) ? cc[nn]
                                        : __builtin_fmaf(m0.x, cc[nn], m0.y);
            #pragma unroll
            for (int m = 0; m < 4; ++m) {
                float cr = __builtin_fmaf(FsS[nn][m], cin, GsS[nn][m]);
                #pragma unroll
                for (int j = 0; j < 4; ++j) {
                    cr = __builtin_fmaf(acc[m][2 + nn][j], cr, acc[m][nn][j]);
                    const int sg = b * S_ + sc * SC + sw * 64 + m * 16 + fq * 4 + j;
                    out[(size_t)sg * H_ + hs * HS + hh] = acc[m][4 + nn][j] * cr;
                }
            }
            cc[nn] = __builtin_fmaf(m1.x, __builtin_fmaf(m0.x, cc[nn], m0.y), m1.y);
        }
        // no post-backfill barrier needed: HOF reads land before their stores
        // issue, and the next kt0 start-barrier precedes any WD1 overwrite.
    }

    // c_last tail: [1,B,H] appended after [B,S,H]
    if (sw == 0 && fq == 0) {
        #pragma unroll
        for (int nn = 0; nn < 2; ++nn)
            out[(size_t)B_ * S_ * H_ + b * H_ + hs * HS + gw * 32 + nn * 16 + fr] = cc[nn];
    }
}

extern "C" void kernel_launch(void* const* d_in, const int* in_sizes, int n_in,
                              void* d_out, int out_size, void* d_ws, size_t ws_size,
                              hipStream_t stream) {
    const float* x = (const float*)d_in[0];
    const float* h = (const float*)d_in[1];
    const float* W = (const float*)d_in[2];
    const float* b = (const float*)d_in[3];
    float* out = (float*)d_out;

    _Float16* xh = (_Float16*)d_ws;
    _Float16* Wh = xh + (size_t)B_ * S_ * K_;

    hipFuncSetAttribute((const void*)qrnn_fused,
                        hipFuncAttributeMaxDynamicSharedMemorySize, LDS_BYTES);

    const int n8x = B_ * S_ * K_ / 8;   // 1048576
    const int n8w = 3 * H_ * K_ / 8;    // 196608
    cvt_xw<<<(n8x + n8w + 255) / 256, 256, 0, stream>>>(x, xh, n8x, W, Wh, n8w);

    qrnn_fused<<<B_ * (H_ / HS), 256, LDS_BYTES, stream>>>(xh, Wh, b, h, out);
}

// Round 11
// 79.352 us; speedup vs baseline: 1.4993x; 1.0610x over previous
//
#include <hip/hip_runtime.h>
#include <hip/hip_bf16.h>
#include <hip/hip_fp16.h>
#include <stdint.h>

typedef __attribute__((ext_vector_type(8))) _Float16 f16x8;
typedef __attribute__((ext_vector_type(4))) float f32x4;

#define B_  32
#define S_  512
#define K_  512
#define H_  1024
#define HS  64           // h-cols per block
#define SC  128          // s-rows per chunk
#define NKT 8            // K_/64
#define NSC 4            // S_/SC

// LDS: x dbuf 2x16K | W dbuf 2x24K = 80KB -> 2 blocks/CU.
// handoff (2 sw x 64 h x {F,G} f32 = 1KB) aliases WD1 rows 184..191: WD1 is
// last read at kt7 (pre-HOF barrier orders), and fully restaged by kt0's
// stage(kt1) glds, which issue only after the next GATE barrier -- by then
// backfill has consumed HOF.
#define XD0 0
#define XD1 16384
#define WD0 32768
#define WD1 57344
#define HOF (WD1 + 24576 - 1024)
#define LDS_BYTES 81920

#define GLDS(src, dst) __builtin_amdgcn_global_load_lds( \
    (const __attribute__((address_space(1))) void*)(src), \
    (__attribute__((address_space(3))) void*)(dst), 16, 0, 0)

__device__ inline float sigm(float v) {
    return __builtin_amdgcn_rcpf(1.f + __expf(-v));
}

// ---------------------------------------------------------------------------
// f32 -> f16 conversion for x and W. 8 elems/thread, 16B stores.
// ---------------------------------------------------------------------------
struct alignas(16) H8 { _Float16 h[8]; };

__global__ __launch_bounds__(256) void cvt_xw(
    const float* __restrict__ x, _Float16* __restrict__ xh, int n8x,
    const float* __restrict__ W, _Float16* __restrict__ Wh, int n8w)
{
    const int t = blockIdx.x * 256 + threadIdx.x;
    const float* src; _Float16* dst; int i;
    if (t < n8x)             { src = x; dst = xh; i = t; }
    else if (t < n8x + n8w)  { src = W; dst = Wh; i = t - n8x; }
    else return;
    const float4* p = (const float4*)(src + (size_t)i * 8);
    const float4 a = p[0], b = p[1];
    H8 o;
    o.h[0] = (_Float16)a.x; o.h[1] = (_Float16)a.y;
    o.h[2] = (_Float16)a.z; o.h[3] = (_Float16)a.w;
    o.h[4] = (_Float16)b.x; o.h[5] = (_Float16)b.y;
    o.h[6] = (_Float16)b.z; o.h[7] = (_Float16)b.w;
    ((H8*)dst)[i] = o;
}

// ---------------------------------------------------------------------------
// Fused GEMM + activations + in-register affine scan + output.
// Round-8 geometry; T3-style sub-phase K-loop (m201 pattern at our scale):
// per kt = GATE{vmcnt(32|0); barrier} then 2 sub-phases, each:
//   {10 ds_read_b128 (af/bf of ks) ; 5 global_load_lds (half of stage kt+1)}
//   -> s_barrier -> lgkmcnt(0)+sched_barrier -> setprio(1) 24 MFMA setprio(0)
//   -> s_barrier (P1's trailing barrier = next kt's GATE barrier).
// Short read bursts + per-phase barriers stagger the 8 resident waves so the
// LDS pipe and MFMA pipe overlap instead of alternating storms.
// ---------------------------------------------------------------------------
__global__ __launch_bounds__(256, 2) void qrnn_fused(
    const _Float16* __restrict__ xh,   // [B*S, K]
    const _Float16* __restrict__ Wh,   // [3H, K]
    const float* __restrict__ bias,    // [3H]
    const float* __restrict__ c0,      // [B, H]
    float* __restrict__ out)           // [B,S,H] ++ [B,H]
{
    extern __shared__ char smem[];

    const int tid  = threadIdx.x;
    const int lane = tid & 63;
    const int wid  = tid >> 6;
    const int gw   = wid & 1;          // h-half (32 h)
    const int sw   = wid >> 1;         // s-half (64 s)
    const int fq   = lane >> 4;
    const int fr   = lane & 15;

    const int bid = blockIdx.x;
    const int b   = (bid & 7) + ((bid >> 7) << 3);
    const int hs  = (bid >> 3) & 15;

    // per-lane h columns (nn = 0,1) and bias
    float bz[2], bff[2], bo[2], cc[2];
    #pragma unroll
    for (int nn = 0; nn < 2; ++nn) {
        const int hcol = hs * HS + gw * 32 + nn * 16 + fr;
        bz[nn]  = bias[hcol];
        bff[nn] = bias[H_ + hcol];
        bo[nn]  = bias[2 * H_ + hcol];
        cc[nn]  = c0[b * H_ + hcol];
    }

    const int srow  = lane >> 3;
    const int scolb = (((lane & 7) ^ (lane >> 3)) << 4);
    const _Float16* xbase = xh + (size_t)(b * S_) * K_;

    // half-stage: ks=0 issues chunks i=0..4, ks=1 issues i=5..9
    auto STAGEH = [&](int sc_, int kt_, int xoff, int woff, int half) {
        #pragma unroll
        for (int i = half * 5; i < half * 5 + 5; ++i) {
            const int cid = wid * 10 + i;          // 0..39 chunks of 1KB
            if (cid < 16) {                        // x tile rows (s')
                const int r = cid * 8 + srow;
                const char* src = (const char*)(xbase + (size_t)(sc_ * SC + r) * K_ + kt_ * 64) + scolb;
                GLDS(src, smem + xoff + cid * 1024);
            } else {                               // W tile rows (0..191)
                const int r = (cid - 16) * 8 + srow;
                const int wrow = (r >> 6) * H_ + hs * HS + (r & 63);
                const char* src = (const char*)(Wh + (size_t)wrow * K_ + kt_ * 64) + scolb;
                GLDS(src, smem + woff + (cid - 16) * 1024);
            }
        }
    };

    STAGEH(0, 0, XD0, WD0, 0);
    STAGEH(0, 0, XD0, WD0, 1);
    asm volatile("s_waitcnt vmcnt(0)" ::: "memory");   // drain prologue stage

    for (int sc = 0; sc < NSC; ++sc) {
        f32x4 acc[4][6] = {};

        #pragma unroll
        for (int kt = 0; kt < NKT; ++kt) {
            const int cur  = kt & 1;
            const int curx = cur ? XD1 : XD0;
            const int curw = cur ? WD1 : WD0;
            const int nxtx = cur ? XD0 : XD1;
            const int nxtw = cur ? WD0 : WD1;

            // --- GATE: cur buffer landed on all waves ----------------------
            if (kt == 0) {
                // 32 backfill stores (newer) may fly; 10 stage loads (older,
                // FIFO) are forced complete.
                asm volatile("s_waitcnt vmcnt(32)" ::: "memory");
            } else {
                asm volatile("s_waitcnt vmcnt(0)" ::: "memory");
            }
            __builtin_amdgcn_s_barrier();
            __builtin_amdgcn_sched_barrier(0);

            #pragma unroll
            for (int ks = 0; ks < 2; ++ks) {
                f16x8 af[4], bf[6];
                #pragma unroll
                for (int m = 0; m < 4; ++m) {
                    const int row = sw * 64 + m * 16 + fr;
                    const int kb  = ks * 64 + fq * 16;
                    af[m] = *(const f16x8*)(smem + curx + row * 128 + (kb ^ ((row & 7) << 4)));
                }
                #pragma unroll
                for (int n = 0; n < 6; ++n) {
                    const int row = (n >> 1) * 64 + gw * 32 + (n & 1) * 16 + fr;
                    const int kb  = ks * 64 + fq * 16;
                    bf[n] = *(const f16x8*)(smem + curw + row * 128 + (kb ^ ((row & 7) << 4)));
                }

                // half-stage for kt+1 issues under this sub-phase
                if (kt + 1 < NKT)      STAGEH(sc, kt + 1, nxtx, nxtw, ks);
                else if (sc + 1 < NSC) STAGEH(sc + 1, 0, nxtx, nxtw, ks);

                __builtin_amdgcn_s_barrier();
                asm volatile("s_waitcnt lgkmcnt(0)" ::: "memory");
                __builtin_amdgcn_sched_barrier(0);
                __builtin_amdgcn_s_setprio(1);
                #pragma unroll
                for (int m = 0; m < 4; ++m)
                    #pragma unroll
                    for (int n = 0; n < 6; ++n)
                        acc[m][n] = __builtin_amdgcn_mfma_f32_16x16x32_f16(
                            af[m], bf[n], acc[m][n], 0, 0, 0);
                __builtin_amdgcn_s_setprio(0);
                if (ks == 0) __builtin_amdgcn_s_barrier();
                // ks==1 trailing barrier = next kt's GATE barrier
            }
        }

        // ---- activations + per-lane affine composition (register-only) ------
        // step: c <- f*c + g, g = (1-f)*z. acc slots after this pass:
        // [m][nn] = g, [m][2+nn] = f, [m][4+nn] = o (all f32).
        float FsS[2][4], GsS[2][4];   // chunk-start -> run(m)-start coeffs
        float FP[2], GP[2];           // wave-total map (exclusive prefix over m)
        #pragma unroll
        for (int nn = 0; nn < 2; ++nn) {
            FP[nn] = 1.f; GP[nn] = 0.f;
            #pragma unroll
            for (int m = 0; m < 4; ++m) {
                float Fr = 1.f, Gr = 0.f;
                #pragma unroll
                for (int j = 0; j < 4; ++j) {
                    const float z = 2.f * sigm(2.f * (acc[m][nn][j] + bz[nn])) - 1.f;
                    const float f = sigm(acc[m][2 + nn][j] + bff[nn]);
                    const float g = (1.f - f) * z;
                    acc[m][nn][j]     = g;
                    acc[m][2 + nn][j] = f;
                    acc[m][4 + nn][j] = sigm(acc[m][4 + nn][j] + bo[nn]);
                    Gr = __builtin_fmaf(f, Gr, g);
                    Fr = f * Fr;
                }
                // Kogge-Stone over fq (4 groups of 16 lanes)
                float F1 = __shfl(Fr, lane - 16), G1 = __shfl(Gr, lane - 16);
                if (fq >= 1) { Gr = __builtin_fmaf(Fr, G1, Gr); Fr = Fr * F1; }
                float F2 = __shfl(Fr, lane - 32), G2 = __shfl(Gr, lane - 32);
                if (fq >= 2) { Gr = __builtin_fmaf(Fr, G2, Gr); Fr = Fr * F2; }
                float FE = __shfl(Fr, lane - 16), GE = __shfl(Gr, lane - 16);
                if (fq == 0) { FE = 1.f; GE = 0.f; }
                const float FM = __shfl(Fr, 48 + fr);   // full 16-step map of m
                const float GM = __shfl(Gr, 48 + fr);
                FsS[nn][m] = FE * FP[nn];
                GsS[nn][m] = __builtin_fmaf(FE, GP[nn], GE);
                GP[nn] = __builtin_fmaf(FM, GP[nn], GM);
                FP[nn] = FM * FP[nn];
            }
        }

        // all waves done reading WD1 (kt7 frags) before HOF write aliases it
        __builtin_amdgcn_s_barrier();

        // ---- handoff: per-h wave-total (F,G) between sw waves ---------------
        if (fq == 0) {
            #pragma unroll
            for (int nn = 0; nn < 2; ++nn) {
                const int hh = gw * 32 + nn * 16 + fr;
                *(float2*)(smem + HOF + sw * 512 + hh * 8) = make_float2(FP[nn], GP[nn]);
            }
        }
        asm volatile("s_waitcnt lgkmcnt(0)" ::: "memory");
        __builtin_amdgcn_s_barrier();

        // ---- backfill + out stores ------------------------------------------
        #pragma unroll
        for (int nn = 0; nn < 2; ++nn) {
            const int hh = gw * 32 + nn * 16 + fr;
            const float2 m0 = *(const float2*)(smem + HOF + hh * 8);
            const float2 m1 = *(const float2*)(smem + HOF + 512 + hh * 8);
            const float cin = (sw == 0) ? cc[nn]
                                        : __builtin_fmaf(m0.x, cc[nn], m0.y);
            #pragma unroll
            for (int m = 0; m < 4; ++m) {
                float cr = __builtin_fmaf(FsS[nn][m], cin, GsS[nn][m]);
                #pragma unroll
                for (int j = 0; j < 4; ++j) {
                    cr = __builtin_fmaf(acc[m][2 + nn][j], cr, acc[m][nn][j]);
                    const int sg = b * S_ + sc * SC + sw * 64 + m * 16 + fq * 4 + j;
                    out[(size_t)sg * H_ + hs * HS + hh] = acc[m][4 + nn][j] * cr;
                }
            }
            cc[nn] = __builtin_fmaf(m1.x, __builtin_fmaf(m0.x, cc[nn], m0.y), m1.y);
        }
        // HOF reads consumed before these stores issue; next GATE barrier
        // precedes any WD1/HOF overwrite.
    }

    // c_last tail: [1,B,H] appended after [B,S,H]
    if (sw == 0 && fq == 0) {
        #pragma unroll
        for (int nn = 0; nn < 2; ++nn)
            out[(size_t)B_ * S_ * H_ + b * H_ + hs * HS + gw * 32 + nn * 16 + fr] = cc[nn];
    }
}

extern "C" void kernel_launch(void* const* d_in, const int* in_sizes, int n_in,
                              void* d_out, int out_size, void* d_ws, size_t ws_size,
                              hipStream_t stream) {
    const float* x = (const float*)d_in[0];
    const float* h = (const float*)d_in[1];
    const float* W = (const float*)d_in[2];
    const float* b = (const float*)d_in[3];
    float* out = (float*)d_out;

    _Float16* xh = (_Float16*)d_ws;
    _Float16* Wh = xh + (size_t)B_ * S_ * K_;

    hipFuncSetAttribute((const void*)qrnn_fused,
                        hipFuncAttributeMaxDynamicSharedMemorySize, LDS_BYTES);

    const int n8x = B_ * S_ * K_ / 8;   // 1048576
    const int n8w = 3 * H_ * K_ / 8;    // 196608
    cvt_xw<<<(n8x + n8w + 255) / 256, 256, 0, stream>>>(x, xh, n8x, W, Wh, n8w);

    qrnn_fused<<<B_ * (H_ / HS), 256, LDS_BYTES, stream>>>(xh, Wh, b, h, out);
}